// Round 3
// baseline (408.234 us; speedup 1.0000x reference)
//
#include <hip/hip_runtime.h>
#include <hip/hip_bf16.h>
#include <stdint.h>

typedef unsigned short u16;
typedef __attribute__((ext_vector_type(4))) unsigned short u16x4;
typedef __attribute__((ext_vector_type(8))) short short8;
typedef __attribute__((ext_vector_type(4))) float f32x4;

__device__ inline u16 f2b(float f) {
  uint32_t u = __builtin_bit_cast(uint32_t, f);
  u += 0x7fffu + ((u >> 16) & 1u);   // RNE round to bf16
  return (u16)(u >> 16);
}

// ---------------- convert x: fp32 -> bf16 ----------------
__global__ __launch_bounds__(256) void cvt_f32_bf16(const float* __restrict__ in,
                                                    u16* __restrict__ out, long n) {
  long i = ((long)blockIdx.x * blockDim.x + threadIdx.x) * 4;
  if (i + 3 < n) {
    float4 v = *(const float4*)(in + i);
    u16x4 o = { f2b(v.x), f2b(v.y), f2b(v.z), f2b(v.w) };
    *(u16x4*)(out + i) = o;
  }
}

// ---------------- transpose + convert W: [R,C] fp32 -> [C,R] bf16 ----------------
__global__ __launch_bounds__(256) void transpose_cvt(const float* __restrict__ in,
                                                     u16* __restrict__ out, int R, int C) {
  __shared__ float tile[32][33];
  int c0 = blockIdx.x * 32, r0 = blockIdx.y * 32;
#pragma unroll
  for (int j = 0; j < 32; j += 8)
    tile[threadIdx.y + j][threadIdx.x] = in[(long)(r0 + threadIdx.y + j) * C + c0 + threadIdx.x];
  __syncthreads();
#pragma unroll
  for (int j = 0; j < 32; j += 8)
    out[(long)(c0 + threadIdx.y + j) * R + r0 + threadIdx.x] = f2b(tile[threadIdx.x][threadIdx.y + j]);
}

// ---------------- bf16 transpose: in [R,C] (ld=ldin) -> out [C,R] (ld=ldout) ----------------
__global__ __launch_bounds__(256) void transpose_u16(const u16* __restrict__ in,
                                                     u16* __restrict__ out,
                                                     int ldin, int ldout) {
  __shared__ u16 tile[32][33];
  int c0 = blockIdx.x * 32, r0 = blockIdx.y * 32;
#pragma unroll
  for (int j = 0; j < 32; j += 8)
    tile[threadIdx.y + j][threadIdx.x] = in[(long)(r0 + threadIdx.y + j) * ldin + c0 + threadIdx.x];
  __syncthreads();
#pragma unroll
  for (int j = 0; j < 32; j += 8)
    out[(long)(c0 + threadIdx.y + j) * ldout + r0 + threadIdx.x] = tile[threadIdx.x][threadIdx.y + j];
}

// ---------------- concat biases [1024]x3 -> [3072] ----------------
__global__ __launch_bounds__(256) void concat_bias(const float* __restrict__ bq,
                                                   const float* __restrict__ bk,
                                                   const float* __restrict__ bv,
                                                   float* __restrict__ out) {
  int i = blockIdx.x * 256 + threadIdx.x;
  if (i < 3072)
    out[i] = i < 1024 ? bq[i] : (i < 2048 ? bk[i - 1024] : bv[i - 2048]);
}

// ---------------- 128x128 bt-GEMM, BK=32, double-buffered single-barrier K-loop ----
// C[m][n] = sum_k A[m][k] * Bt[n][k]
// mode 0: bf16 out, + bias[col]   (QKV projection)
// mode 2: fp32 out, *scale + mask (scores)
// mode 3: fp32 out                (PV -> d_out)
#define BM 128
#define BN 128
#define BK 32

__device__ inline void load_lds16(const void* g, void* l) {
  __builtin_amdgcn_global_load_lds((const __attribute__((address_space(1))) void*)g,
                                   (__attribute__((address_space(3))) void*)l, 16, 0, 0);
}

__global__ __launch_bounds__(256, 2) void gemm_bt(
    const u16* __restrict__ A, const u16* __restrict__ Bt, void* __restrict__ C,
    const float* __restrict__ bias, const float* __restrict__ mask,
    int K, int lda, int ldb, int ldc, int ldmask,
    long sA, long sB, long sC, long sMask,
    float scale, int mode)
{
  const int z = blockIdx.z;
  A += z * sA;
  Bt += z * sB;
  const long cbase = z * sC;
  const long mbase = z * sMask;

  // double-buffered: 2 x (8KB A + 8KB B) = 32 KB
  __shared__ __align__(16) u16 lA[2][BM * BK];
  __shared__ __align__(16) u16 lB[2][BN * BK];

  const int t = threadIdx.x;
  const int lane = t & 63;
  const int wave = t >> 6;
  const int wr = wave >> 1, wc = wave & 1;
  const int m0 = blockIdx.y * BM, n0 = blockIdx.x * BN;

  // Staging: row r of a tile has 4 chunks of 8 u16; LDS slot s of row r holds
  // global chunk s ^ ((r>>1)&3)  (XOR swizzle; fragment reads land 2-way = free).
  // Thread t, issue i: LDS linear dest (i*256+t)*8 -> row (t>>2)+i*64, slot t&3.
  const int chunk = (t & 3) ^ ((t >> 3) & 3);          // global chunk this thread fetches
  const u16* aS = A + (long)(m0 + (t >> 2)) * lda + chunk * 8;
  const u16* bS = Bt + (long)(n0 + (t >> 2)) * ldb + chunk * 8;
  const long aStep = (long)64 * lda;                   // issue-1 row offset
  const long bStep = (long)64 * ldb;

  f32x4 acc[4][4] = {};
  const int fr = lane & 15;
  const int q4 = lane >> 4;                            // 0..3 -> k-chunk of this lane
  const int slotK = (q4 ^ ((fr >> 1) & 3)) * 8;        // swizzled LDS k-slot (u16 units)

  // prologue: stage tile 0 into buffer 0
  load_lds16(aS,         &lA[0][t * 8]);
  load_lds16(aS + aStep, &lA[0][(256 + t) * 8]);
  load_lds16(bS,         &lB[0][t * 8]);
  load_lds16(bS + bStep, &lB[0][(256 + t) * 8]);

  int cur = 0;
  for (int k0 = 0; k0 < K; k0 += BK) {
    __syncthreads();   // drains loads issued last iter (they overlapped that compute)
    if (k0 + BK < K) {
      const u16* a2 = aS + k0 + BK;
      const u16* b2 = bS + k0 + BK;
      const int nxt = cur ^ 1;
      load_lds16(a2,         &lA[nxt][t * 8]);
      load_lds16(a2 + aStep, &lA[nxt][(256 + t) * 8]);
      load_lds16(b2,         &lB[nxt][t * 8]);
      load_lds16(b2 + bStep, &lB[nxt][(256 + t) * 8]);
    }
    short8 aF[4], bF[4];
#pragma unroll
    for (int i = 0; i < 4; i++)
      aF[i] = *(const short8*)&lA[cur][(wr * 64 + i * 16 + fr) * BK + slotK];
#pragma unroll
    for (int j = 0; j < 4; j++)
      bF[j] = *(const short8*)&lB[cur][(wc * 64 + j * 16 + fr) * BK + slotK];
#pragma unroll
    for (int i = 0; i < 4; i++)
#pragma unroll
      for (int j = 0; j < 4; j++)
        acc[i][j] = __builtin_amdgcn_mfma_f32_16x16x32_bf16(aF[i], bF[j], acc[i][j], 0, 0, 0);
    cur ^= 1;
  }

  // epilogue: C/D layout col = lane&15, row = (lane>>4)*4 + r
  const int r0 = q4 * 4;
#pragma unroll
  for (int i = 0; i < 4; i++) {
#pragma unroll
    for (int j = 0; j < 4; j++) {
      const int row = m0 + wr * 64 + i * 16 + r0;
      const int col = n0 + wc * 64 + j * 16 + fr;
#pragma unroll
      for (int r = 0; r < 4; r++) {
        float v = acc[i][j][r];
        long idx = cbase + (long)(row + r) * ldc + col;
        if (mode == 0)      ((u16*)C)[idx] = f2b(v + bias[col]);
        else if (mode == 2) ((float*)C)[idx] = v * scale + mask[mbase + (long)(row + r) * ldmask + col];
        else                ((float*)C)[idx] = v;
      }
    }
  }
}

// ---------------- row softmax: fp32 scores [2048] -> bf16 P in-place ----------------
__global__ __launch_bounds__(256) void softmax_rows(float* __restrict__ scores) {
  const long row = blockIdx.x;
  float* s = scores + row * 2048;
  u16* p = (u16*)s;                 // in-place: bf16 row overlays fp32 row
  const int t = threadIdx.x;
  const int wave = t >> 6;

  float4 v0 = *(const float4*)(s + 4 * t);
  float4 v1 = *(const float4*)(s + 1024 + 4 * t);

  float m = fmaxf(fmaxf(fmaxf(v0.x, v0.y), fmaxf(v0.z, v0.w)),
                  fmaxf(fmaxf(v1.x, v1.y), fmaxf(v1.z, v1.w)));
#pragma unroll
  for (int off = 32; off > 0; off >>= 1) m = fmaxf(m, __shfl_xor(m, off));
  __shared__ float redm[4];
  if ((t & 63) == 0) redm[wave] = m;
  __syncthreads();
  m = fmaxf(fmaxf(redm[0], redm[1]), fmaxf(redm[2], redm[3]));

  float e[8];
  e[0] = __expf(v0.x - m); e[1] = __expf(v0.y - m);
  e[2] = __expf(v0.z - m); e[3] = __expf(v0.w - m);
  e[4] = __expf(v1.x - m); e[5] = __expf(v1.y - m);
  e[6] = __expf(v1.z - m); e[7] = __expf(v1.w - m);
  float sum = ((e[0] + e[1]) + (e[2] + e[3])) + ((e[4] + e[5]) + (e[6] + e[7]));
#pragma unroll
  for (int off = 32; off > 0; off >>= 1) sum += __shfl_xor(sum, off);
  __shared__ float reds[4];
  if ((t & 63) == 0) reds[wave] = sum;
  __syncthreads();
  sum = (reds[0] + reds[1]) + (reds[2] + reds[3]);
  float inv = 1.0f / sum;

  u16x4 o0 = { f2b(e[0] * inv), f2b(e[1] * inv), f2b(e[2] * inv), f2b(e[3] * inv) };
  u16x4 o1 = { f2b(e[4] * inv), f2b(e[5] * inv), f2b(e[6] * inv), f2b(e[7] * inv) };
  // all loads of this row completed before the barriers above -> safe in-place
  *(u16x4*)(p + 4 * t) = o0;
  *(u16x4*)(p + 1024 + 4 * t) = o1;
}

// ---------------- launch ----------------
extern "C" void kernel_launch(void* const* d_in, const int* in_sizes, int n_in,
                              void* d_out, int out_size, void* d_ws, size_t ws_size,
                              hipStream_t stream) {
  const float* x    = (const float*)d_in[0];   // [4,2048,1024]
  const float* mask = (const float*)d_in[1];   // [4,2048,2048]
  const float* Wq   = (const float*)d_in[2];   // [1024,1024]
  const float* bq   = (const float*)d_in[3];
  const float* Wk   = (const float*)d_in[4];
  const float* bk   = (const float*)d_in[5];
  const float* Wv   = (const float*)d_in[6];
  const float* bv   = (const float*)d_in[7];
  float* out = (float*)d_out;

  // workspace layout (total ~157.3 MB)
  char* w = (char*)d_ws;
  u16*   xb    = (u16*)(w);                 // x bf16      [8192,1024]  16.78 MB
  u16*   wT    = (u16*)(w + 16777216);      // [Wq;Wk;Wv]^T bf16 [3072,1024]  6.29 MB
  float* biasC = (float*)(w + 23068672);    // concat bias [3072]       12 KB
  u16*   QKV   = (u16*)(w + 23081088);      // QKV bf16    [8192,3072]  50.33 MB
  u16*   Vt    = (u16*)(w + 73414016);      // V^T bf16    [1024,8192]  16.78 MB
  float* sc    = (float*)(w + 90191232);    // scores fp32 [4,2048,2048] 67.11 MB (P bf16 overlays)

  // 1. converts / packing
  cvt_f32_bf16<<<8192, 256, 0, stream>>>(x, xb, 8192L * 1024);
  dim3 tb(32, 8);
  transpose_cvt<<<dim3(32, 32), tb, 0, stream>>>(Wq, wT,              1024, 1024);
  transpose_cvt<<<dim3(32, 32), tb, 0, stream>>>(Wk, wT + 1024 * 1024, 1024, 1024);
  transpose_cvt<<<dim3(32, 32), tb, 0, stream>>>(Wv, wT + 2048 * 1024, 1024, 1024);
  concat_bias<<<12, 256, 0, stream>>>(bq, bk, bv, biasC);

  // 2. fused QKV projection: [8192,1024] x [3072,1024]^T -> [8192,3072] bf16
  gemm_bt<<<dim3(24, 64, 1), 256, 0, stream>>>(xb, wT, QKV, biasC, nullptr,
      1024, 1024, 1024, 3072, 0, 0, 0, 0, 0, 1.0f, 0);

  // 3. V^T for the PV GEMM: [8192,1024] slice -> [1024,8192]
  transpose_u16<<<dim3(32, 256), tb, 0, stream>>>(QKV + 2048, Vt, 3072, 8192);

  // 4. scores = Q K^T * 1/32 + mask   (z = batch)
  gemm_bt<<<dim3(16, 16, 4), 256, 0, stream>>>(QKV, QKV + 1024, sc, nullptr, mask,
      1024, 3072, 3072, 2048, 2048,
      2048L * 3072, 2048L * 3072, 2048L * 2048, 2048L * 2048, 0.03125f, 2);

  // 5. softmax rows -> P bf16 (in-place over scores)
  softmax_rows<<<8192, 256, 0, stream>>>(sc);

  // 6. out = P V   (A = P bf16 with lda=4096 over the fp32 rows; Bt = V^T)
  gemm_bt<<<dim3(8, 16, 4), 256, 0, stream>>>((const u16*)sc, Vt, out, nullptr, nullptr,
      2048, 4096, 8192, 1024, 0,
      2048L * 4096, 2048L, 2048L * 1024, 0, 1.0f, 3);
}

// Round 4
// 328.504 us; speedup vs baseline: 1.2427x; 1.2427x over previous
//
#include <hip/hip_runtime.h>
#include <hip/hip_bf16.h>
#include <stdint.h>

typedef unsigned short u16;
typedef __attribute__((ext_vector_type(4))) unsigned short u16x4;
typedef __attribute__((ext_vector_type(8))) short short8;
typedef __attribute__((ext_vector_type(4))) float f32x4;

__device__ inline u16 f2b(float f) {
  uint32_t u = __builtin_bit_cast(uint32_t, f);
  u += 0x7fffu + ((u >> 16) & 1u);   // RNE round to bf16
  return (u16)(u >> 16);
}

// ---------------- convert x: fp32 -> bf16 ----------------
__global__ __launch_bounds__(256) void cvt_f32_bf16(const float* __restrict__ in,
                                                    u16* __restrict__ out, long n) {
  long i = ((long)blockIdx.x * blockDim.x + threadIdx.x) * 4;
  if (i + 3 < n) {
    float4 v = *(const float4*)(in + i);
    u16x4 o = { f2b(v.x), f2b(v.y), f2b(v.z), f2b(v.w) };
    *(u16x4*)(out + i) = o;
  }
}

// ---------------- transpose + convert W: [R,C] fp32 -> [C,R] bf16 ----------------
__global__ __launch_bounds__(256) void transpose_cvt(const float* __restrict__ in,
                                                     u16* __restrict__ out, int R, int C) {
  __shared__ float tile[32][33];
  int c0 = blockIdx.x * 32, r0 = blockIdx.y * 32;
#pragma unroll
  for (int j = 0; j < 32; j += 8)
    tile[threadIdx.y + j][threadIdx.x] = in[(long)(r0 + threadIdx.y + j) * C + c0 + threadIdx.x];
  __syncthreads();
#pragma unroll
  for (int j = 0; j < 32; j += 8)
    out[(long)(c0 + threadIdx.y + j) * R + r0 + threadIdx.x] = f2b(tile[threadIdx.x][threadIdx.y + j]);
}

// ---------------- bf16 transpose: in [R,C] (ld=ldin) -> out [C,R] (ld=ldout) ----------------
__global__ __launch_bounds__(256) void transpose_u16(const u16* __restrict__ in,
                                                     u16* __restrict__ out,
                                                     int ldin, int ldout) {
  __shared__ u16 tile[32][33];
  int c0 = blockIdx.x * 32, r0 = blockIdx.y * 32;
#pragma unroll
  for (int j = 0; j < 32; j += 8)
    tile[threadIdx.y + j][threadIdx.x] = in[(long)(r0 + threadIdx.y + j) * ldin + c0 + threadIdx.x];
  __syncthreads();
#pragma unroll
  for (int j = 0; j < 32; j += 8)
    out[(long)(c0 + threadIdx.y + j) * ldout + r0 + threadIdx.x] = tile[threadIdx.x][threadIdx.y + j];
}

// ---------------- concat biases [1024]x3 -> [3072] ----------------
__global__ __launch_bounds__(256) void concat_bias(const float* __restrict__ bq,
                                                   const float* __restrict__ bk,
                                                   const float* __restrict__ bv,
                                                   float* __restrict__ out) {
  int i = blockIdx.x * 256 + threadIdx.x;
  if (i < 3072)
    out[i] = i < 1024 ? bq[i] : (i < 2048 ? bk[i - 1024] : bv[i - 2048]);
}

// ---------------- 128x128 bt-GEMM, BK=64, XOR-swizzled LDS (round-2 structure) ----
// C[m][n] = sum_k A[m][k] * Bt[n][k]
// mode 0: bf16 out, + bias[col]   (QKV projection)
// mode 3: fp32 out                (scores raw / PV -> d_out)
#define BM 128
#define BN 128
#define BK 64

__device__ inline void load_lds16(const void* g, void* l) {
  __builtin_amdgcn_global_load_lds((const __attribute__((address_space(1))) void*)g,
                                   (__attribute__((address_space(3))) void*)l, 16, 0, 0);
}

__global__ __launch_bounds__(256, 2) void gemm_bt(
    const u16* __restrict__ A, const u16* __restrict__ Bt, void* __restrict__ C,
    const float* __restrict__ bias,
    int K, int lda, int ldb, int ldc,
    long sA, long sB, long sC,
    int mode)
{
  const int z = blockIdx.z;
  A += z * sA;
  Bt += z * sB;
  const long cbase = z * sC;

  __shared__ __align__(16) u16 lA[BM * BK];   // 16 KB
  __shared__ __align__(16) u16 lB[BN * BK];   // 16 KB

  const int t = threadIdx.x;
  const int lane = t & 63;
  const int wave = t >> 6;
  const int wr = wave >> 1, wc = wave & 1;
  const int m0 = blockIdx.y * BM, n0 = blockIdx.x * BN;

  // Staging: LDS is [128 rows][8 chunks of 8 u16]; LDS slot s of row r holds
  // global chunk s ^ (r&7)  (XOR swizzle -> conflict-free ds_read_b128).
  // Thread t, issue i: LDS dest (i*256+t)*8 -> row = (t>>3)+i*32, slot = t&7.
  const int srow = t >> 3;                       // 0..31
  const int schunk = (t & 7) ^ (srow & 7);       // global chunk this thread fetches
  const u16* aS = A + (long)(m0 + srow) * lda + schunk * 8;
  const u16* bS = Bt + (long)(n0 + srow) * ldb + schunk * 8;

  f32x4 acc[4][4] = {};
  const int fr = lane & 15;
  const int q4 = lane >> 4;                      // 0..3

  for (int k0 = 0; k0 < K; k0 += BK) {
    __syncthreads();                 // prior ds_reads done before overwrite
#pragma unroll
    for (int i = 0; i < 4; i++) {
      load_lds16(aS + k0 + (long)(i * 32) * lda, &lA[(i * 256 + t) * 8]);
      load_lds16(bS + k0 + (long)(i * 32) * ldb, &lB[(i * 256 + t) * 8]);
    }
    __syncthreads();                 // drain global_load_lds
#pragma unroll
    for (int kk = 0; kk < 2; kk++) {
      const int ch = kk * 4 + q4;    // global chunk for this lane's k-slice
      short8 aF[4], bF[4];
#pragma unroll
      for (int i = 0; i < 4; i++) {
        int row = wr * 64 + i * 16 + fr;
        aF[i] = *(const short8*)&lA[row * BK + ((ch ^ (row & 7)) * 8)];
      }
#pragma unroll
      for (int j = 0; j < 4; j++) {
        int row = wc * 64 + j * 16 + fr;
        bF[j] = *(const short8*)&lB[row * BK + ((ch ^ (row & 7)) * 8)];
      }
#pragma unroll
      for (int i = 0; i < 4; i++)
#pragma unroll
        for (int j = 0; j < 4; j++)
          acc[i][j] = __builtin_amdgcn_mfma_f32_16x16x32_bf16(aF[i], bF[j], acc[i][j], 0, 0, 0);
    }
  }

  // epilogue: C/D layout col = lane&15, row = (lane>>4)*4 + r
  const int r0 = q4 * 4;
#pragma unroll
  for (int i = 0; i < 4; i++) {
#pragma unroll
    for (int j = 0; j < 4; j++) {
      const int row = m0 + wr * 64 + i * 16 + r0;
      const int col = n0 + wc * 64 + j * 16 + fr;
#pragma unroll
      for (int r = 0; r < 4; r++) {
        float v = acc[i][j][r];
        long idx = cbase + (long)(row + r) * ldc + col;
        if (mode == 0)      ((u16*)C)[idx] = f2b(v + bias[col]);
        else                ((float*)C)[idx] = v;
      }
    }
  }
}

// ---------------- row softmax with fused scale+mask ----------------
// logits = scores*scale + mask; writes bf16 P in-place over the fp32 row
__global__ __launch_bounds__(256) void softmax_rows(float* __restrict__ scores,
                                                    const float* __restrict__ mask,
                                                    float scale) {
  const long row = blockIdx.x;
  float* s = scores + row * 2048;
  const float* mk = mask + row * 2048;     // [B,S,S] same linear layout as scores
  u16* p = (u16*)s;                        // in-place: bf16 row overlays fp32 row
  const int t = threadIdx.x;
  const int wave = t >> 6;

  float4 v0 = *(const float4*)(s + 4 * t);
  float4 v1 = *(const float4*)(s + 1024 + 4 * t);
  float4 m0 = *(const float4*)(mk + 4 * t);
  float4 m1 = *(const float4*)(mk + 1024 + 4 * t);
  v0.x = v0.x * scale + m0.x; v0.y = v0.y * scale + m0.y;
  v0.z = v0.z * scale + m0.z; v0.w = v0.w * scale + m0.w;
  v1.x = v1.x * scale + m1.x; v1.y = v1.y * scale + m1.y;
  v1.z = v1.z * scale + m1.z; v1.w = v1.w * scale + m1.w;

  float m = fmaxf(fmaxf(fmaxf(v0.x, v0.y), fmaxf(v0.z, v0.w)),
                  fmaxf(fmaxf(v1.x, v1.y), fmaxf(v1.z, v1.w)));
#pragma unroll
  for (int off = 32; off > 0; off >>= 1) m = fmaxf(m, __shfl_xor(m, off));
  __shared__ float redm[4];
  if ((t & 63) == 0) redm[wave] = m;
  __syncthreads();
  m = fmaxf(fmaxf(redm[0], redm[1]), fmaxf(redm[2], redm[3]));

  float e[8];
  e[0] = __expf(v0.x - m); e[1] = __expf(v0.y - m);
  e[2] = __expf(v0.z - m); e[3] = __expf(v0.w - m);
  e[4] = __expf(v1.x - m); e[5] = __expf(v1.y - m);
  e[6] = __expf(v1.z - m); e[7] = __expf(v1.w - m);
  float sum = ((e[0] + e[1]) + (e[2] + e[3])) + ((e[4] + e[5]) + (e[6] + e[7]));
#pragma unroll
  for (int off = 32; off > 0; off >>= 1) sum += __shfl_xor(sum, off);
  __shared__ float reds[4];
  if ((t & 63) == 0) reds[wave] = sum;
  __syncthreads();
  sum = (reds[0] + reds[1]) + (reds[2] + reds[3]);
  float inv = 1.0f / sum;

  u16x4 o0 = { f2b(e[0] * inv), f2b(e[1] * inv), f2b(e[2] * inv), f2b(e[3] * inv) };
  u16x4 o1 = { f2b(e[4] * inv), f2b(e[5] * inv), f2b(e[6] * inv), f2b(e[7] * inv) };
  // all loads of this row completed before the barriers above -> safe in-place
  *(u16x4*)(p + 4 * t) = o0;
  *(u16x4*)(p + 1024 + 4 * t) = o1;
}

// ---------------- launch ----------------
extern "C" void kernel_launch(void* const* d_in, const int* in_sizes, int n_in,
                              void* d_out, int out_size, void* d_ws, size_t ws_size,
                              hipStream_t stream) {
  const float* x    = (const float*)d_in[0];   // [4,2048,1024]
  const float* mask = (const float*)d_in[1];   // [4,2048,2048]
  const float* Wq   = (const float*)d_in[2];   // [1024,1024]
  const float* bq   = (const float*)d_in[3];
  const float* Wk   = (const float*)d_in[4];
  const float* bk   = (const float*)d_in[5];
  const float* Wv   = (const float*)d_in[6];
  const float* bv   = (const float*)d_in[7];
  float* out = (float*)d_out;

  // workspace layout (total ~157.3 MB)
  char* w = (char*)d_ws;
  u16*   xb    = (u16*)(w);                 // x bf16      [8192,1024]  16.78 MB
  u16*   wT    = (u16*)(w + 16777216);      // [Wq;Wk;Wv]^T bf16 [3072,1024]  6.29 MB
  float* biasC = (float*)(w + 23068672);    // concat bias [3072]       12 KB
  u16*   QKV   = (u16*)(w + 23081088);      // QKV bf16    [8192,3072]  50.33 MB
  u16*   Vt    = (u16*)(w + 73414016);      // V^T bf16    [1024,8192]  16.78 MB
  float* sc    = (float*)(w + 90191232);    // scores fp32 [4,2048,2048] 67.11 MB (P bf16 overlays)

  // 1. converts / packing
  cvt_f32_bf16<<<8192, 256, 0, stream>>>(x, xb, 8192L * 1024);
  dim3 tb(32, 8);
  transpose_cvt<<<dim3(32, 32), tb, 0, stream>>>(Wq, wT,              1024, 1024);
  transpose_cvt<<<dim3(32, 32), tb, 0, stream>>>(Wk, wT + 1024 * 1024, 1024, 1024);
  transpose_cvt<<<dim3(32, 32), tb, 0, stream>>>(Wv, wT + 2048 * 1024, 1024, 1024);
  concat_bias<<<12, 256, 0, stream>>>(bq, bk, bv, biasC);

  // 2. fused QKV projection: [8192,1024] x [3072,1024]^T -> [8192,3072] bf16
  gemm_bt<<<dim3(24, 64, 1), 256, 0, stream>>>(xb, wT, QKV, biasC,
      1024, 1024, 1024, 3072, 0, 0, 0, 0);

  // 3. V^T for the PV GEMM: [8192,1024] slice -> [1024,8192]
  transpose_u16<<<dim3(32, 256), tb, 0, stream>>>(QKV + 2048, Vt, 3072, 8192);

  // 4. scores = Q K^T raw fp32 (scale+mask deferred to softmax)
  gemm_bt<<<dim3(16, 16, 4), 256, 0, stream>>>(QKV, QKV + 1024, sc, nullptr,
      1024, 3072, 3072, 2048,
      2048L * 3072, 2048L * 3072, 2048L * 2048, 3);

  // 5. softmax rows (fused *1/32 + mask) -> P bf16 (in-place over scores)
  softmax_rows<<<8192, 256, 0, stream>>>(sc, mask, 0.03125f);

  // 6. out = P V   (A = P bf16 with lda=4096 over the fp32 rows; Bt = V^T)
  gemm_bt<<<dim3(8, 16, 4), 256, 0, stream>>>((const u16*)sc, Vt, out, nullptr,
      2048, 4096, 8192, 1024,
      2048L * 4096, 2048L, 2048L * 1024, 3);
}